// Round 3
// baseline (313.118 us; speedup 1.0000x reference)
//
#include <hip/hip_runtime.h>

#define NN 500
#define BB 32
#define TT 12
#define EMB 10

// ---------------- K1: S = softmax(relu(E E^T) with diag=stay), rows ----------------
__global__ __launch_bounds__(256) void k_softmaxS(const float* __restrict__ E,
                                                  const int* __restrict__ stay,
                                                  float* __restrict__ S) {
    const int i = blockIdx.x;
    const int tid = threadIdx.x;
    __shared__ float row[NN];
    __shared__ float red[256];
    float ei[EMB];
#pragma unroll
    for (int d = 0; d < EMB; ++d) ei[d] = E[i * EMB + d];
    const float stayf = (float)stay[0];

    float lmax = -1e30f;
    for (int j = tid; j < NN; j += 256) {
        float acc = 0.f;
#pragma unroll
        for (int d = 0; d < EMB; ++d) acc += ei[d] * E[j * EMB + d];
        float v = acc > 0.f ? acc : 0.f;
        if (j == i) v = stayf;
        row[j] = v;
        lmax = fmaxf(lmax, v);
    }
    red[tid] = lmax;
    __syncthreads();
    for (int s = 128; s > 0; s >>= 1) {
        if (tid < s) red[tid] = fmaxf(red[tid], red[tid + s]);
        __syncthreads();
    }
    const float rmax = red[0];
    __syncthreads();

    float lsum = 0.f;
    for (int j = tid; j < NN; j += 256) {
        float e = __expf(row[j] - rmax);
        row[j] = e;
        lsum += e;
    }
    red[tid] = lsum;
    __syncthreads();
    for (int s = 128; s > 0; s >>= 1) {
        if (tid < s) red[tid] += red[tid + s];
        __syncthreads();
    }
    const float inv = 1.0f / red[0];
    for (int j = tid; j < NN; j += 256) S[i * NN + j] = row[j] * inv;
}

// ---------------- K2/K3: y[b,n] = sum_m S[n,m] * xin[b,m] (wave per row) ----------------
__global__ __launch_bounds__(256) void k_matvecS(const float* __restrict__ S,
                                                 const float* __restrict__ xin,
                                                 float* __restrict__ yout) {
    const int b = blockIdx.y;
    const int w = threadIdx.x >> 6;
    const int lane = threadIdx.x & 63;
    const int n = blockIdx.x * 4 + w;
    const float* xb = xin + b * NN;
    const float* Sr = S + n * NN;
    float acc = 0.f;
    for (int m = lane; m < NN; m += 64) acc += Sr[m] * xb[m];
#pragma unroll
    for (int off = 32; off > 0; off >>= 1) acc += __shfl_down(acc, off, 64);
    if (lane == 0) yout[b * NN + n] = acc;
}

// ---------------- K4: per-node small weights from embeddings ----------------
__global__ __launch_bounds__(256) void k_smallpre(const float* __restrict__ E,
                                                  const float* __restrict__ wp,
                                                  const float* __restrict__ bp,
                                                  const float* __restrict__ wwsp,
                                                  const float* __restrict__ wwtp,
                                                  float* __restrict__ W,
                                                  float* __restrict__ biasN,
                                                  float* __restrict__ wws,
                                                  float* __restrict__ wwt) {
    const int n = blockIdx.x;
    const int tid = threadIdx.x;
    __shared__ float e[EMB];
    if (tid < EMB) e[tid] = E[n * EMB + tid];
    __syncthreads();
    if (tid < 144) {
        float acc = 0.f;
#pragma unroll
        for (int d = 0; d < EMB; ++d) acc += e[d] * wp[d * 144 + tid];
        W[n * 144 + tid] = acc;
    } else if (tid < 208) {
        const int o = tid - 144;
        float acc = 0.f;
#pragma unroll
        for (int d = 0; d < EMB; ++d) acc += e[d] * bp[d * 64 + o];
        biasN[n * 64 + o] = acc;
    } else if (tid < 216) {
        const int o = tid - 208;
        float acc = 0.f;
#pragma unroll
        for (int d = 0; d < EMB; ++d) acc += e[d] * wwsp[d * 8 + o];
        wws[n * 8 + o] = acc;
    } else if (tid < 224) {
        const int o = tid - 216;
        float acc = 0.f;
#pragma unroll
        for (int d = 0; d < EMB; ++d) acc += e[d] * wwtp[d * 8 + o];
        wwt[n * 8 + o] = acc;
    }
}

// ---------------- K5: M[b,n] = mean_f xws, wsum[b,n] = sum_t xw[b,t,n]*T[t] ----------------
__global__ __launch_bounds__(128) void k_Mwsum(const float* __restrict__ xwin,
                                               const float* __restrict__ S,
                                               const int* __restrict__ bidx,
                                               const int* __restrict__ jumpc,
                                               const float* __restrict__ Tp,
                                               float* __restrict__ M,
                                               float* __restrict__ wsum) {
    const int b = blockIdx.y;
    const int n0 = blockIdx.x * 125;
    const int tid = threadIdx.x;
    __shared__ float xsf[NN];
    __shared__ float Tl[TT];
    const int t0 = bidx[0], t1 = bidx[1], t2 = bidx[2];
    if (tid < TT) Tl[tid] = Tp[tid];
    const float* xb = xwin + (size_t)b * TT * NN;
    for (int m = tid; m < NN; m += 128)
        xsf[m] = xb[t0 * NN + m] + xb[t1 * NN + m] + xb[t2 * NN + m];
    __syncthreads();
    if (tid < 125) {
        const int n = n0 + tid;
        float ws_ = 0.f;
#pragma unroll
        for (int t = 0; t < TT; ++t) ws_ += xb[t * NN + n] * Tl[t];
        const float jc = (float)jumpc[0];
        const float jterm = jc * (2.f * xb[t0 * NN + n] + xb[t1 * NN + n]);
        float acc = 0.f;
        for (int m = 0; m < NN; ++m) acc += xsf[m] * S[m * NN + n];
        M[b * NN + n] = (acc + jterm) * (1.f / 3.f);
        wsum[b * NN + n] = ws_;
    }
}

// ---------------- K6: fused dual conv, 4 rows/block, 2 rows/thread, shuffle halos ----------------
__global__ __launch_bounds__(256, 4) void k_conv(const float* __restrict__ MPG,
                                                 const float* __restrict__ wm,
                                                 const float* __restrict__ bmv,
                                                 const float* __restrict__ wx,
                                                 const float* __restrict__ bxv,
                                                 float* __restrict__ partials) {
    const int b = blockIdx.y;
    const int r0 = blockIdx.x * 4;   // output rows r0..r0+3
    const int tid = threadIdx.x;
    const int g = tid >> 7;          // row-pair group: rows r0+2g, r0+2g+1
    const int tx = tid & 127;
    const int lane = tid & 63;
    const int c0 = tx * 4;
    const bool active = (c0 < NN);

    __shared__ float buf[2][6][512];   // dbuf x 6 staged rows x padded width
    __shared__ float wred[4][8];

    const float* base_b = MPG + (size_t)b * (TT * NN * NN);

    // staging: 6 rows x 125 float4 = 750 float4 per t; thread handles f = tid + k*256
    int s_off[3];     // LDS float offset: row*512 + col
    long g_off[3];    // global offset within one t-slice
    bool s_ok[3], g_ok[3];
#pragma unroll
    for (int k = 0; k < 3; ++k) {
        const int f = tid + k * 256;
        const int row = f / 125;
        const int col = (f - row * 125) * 4;
        s_ok[k] = (f < 750);
        s_off[k] = row * 512 + col;
        const int grow = r0 - 1 + row;
        g_ok[k] = s_ok[k] && (grow >= 0) && (grow < NN);
        g_off[k] = (long)grow * NN + col;
    }

    float accA[8][4], accB[8][4];
#pragma unroll
    for (int c = 0; c < 4; ++c) {
        const float bm = bmv[c];
        const float bx = bxv[c];
#pragma unroll
        for (int v = 0; v < 4; ++v) {
            accA[c][v] = bm; accA[c + 4][v] = bx;
            accB[c][v] = bm; accB[c + 4][v] = bx;
        }
    }

    float4 p[3];
    // prologue: stage t=0
#pragma unroll
    for (int k = 0; k < 3; ++k) {
        p[k] = make_float4(0.f, 0.f, 0.f, 0.f);
        if (g_ok[k]) p[k] = *reinterpret_cast<const float4*>(base_b + g_off[k]);
    }
#pragma unroll
    for (int k = 0; k < 3; ++k)
        if (s_ok[k]) *reinterpret_cast<float4*>(&buf[0][0][0] + s_off[k]) = p[k];
    __syncthreads();

    for (int t = 0; t < TT; ++t) {
        const int pb = t & 1;
        const bool pf = (t + 1) < TT;
        // issue next-tile global loads early (hidden under compute)
        if (pf) {
            const float* tb = base_b + (size_t)(t + 1) * NN * NN;
#pragma unroll
            for (int k = 0; k < 3; ++k) {
                p[k] = make_float4(0.f, 0.f, 0.f, 0.f);
                if (g_ok[k]) p[k] = *reinterpret_cast<const float4*>(tb + g_off[k]);
            }
        }

        const float* wmt = wm + t * 9;
        const float* wxt = wx + t * 9;
#pragma unroll
        for (int j = 0; j < 4; ++j) {
            const float* lr = &buf[pb][2 * g + j][0];
            const float4 R = *reinterpret_cast<const float4*>(&lr[c0]);
            float lf = __shfl_up(R.w, 1, 64);
            if (lane == 0) lf = (c0 == 0) ? 0.f : lr[c0 - 1];
            float rt = __shfl_down(R.x, 1, 64);
            if (lane == 63 || c0 + 4 >= NN) rt = (c0 + 4 < NN) ? lr[c0 + 4] : 0.f;
            const float in[6] = {lf, R.x, R.y, R.z, R.w, rt};
            if (j < 3) {  // row A (r0+2g), kh = j
#pragma unroll
                for (int c = 0; c < 4; ++c) {
                    const float* wm9 = wmt + c * 108 + j * 3;
                    const float* wx9 = wxt + c * 108 + j * 3;
#pragma unroll
                    for (int kw = 0; kw < 3; ++kw) {
                        const float w1 = wm9[kw];
                        const float w2 = wx9[kw];
#pragma unroll
                        for (int v = 0; v < 4; ++v) {
                            accA[c][v] = fmaf(in[v + kw], w1, accA[c][v]);
                            accA[c + 4][v] = fmaf(in[v + kw], w2, accA[c + 4][v]);
                        }
                    }
                }
            }
            if (j > 0) {  // row B (r0+2g+1), kh = j-1
#pragma unroll
                for (int c = 0; c < 4; ++c) {
                    const float* wm9 = wmt + c * 108 + (j - 1) * 3;
                    const float* wx9 = wxt + c * 108 + (j - 1) * 3;
#pragma unroll
                    for (int kw = 0; kw < 3; ++kw) {
                        const float w1 = wm9[kw];
                        const float w2 = wx9[kw];
#pragma unroll
                        for (int v = 0; v < 4; ++v) {
                            accB[c][v] = fmaf(in[v + kw], w1, accB[c][v]);
                            accB[c + 4][v] = fmaf(in[v + kw], w2, accB[c + 4][v]);
                        }
                    }
                }
            }
        }

        if (pf) {
#pragma unroll
            for (int k = 0; k < 3; ++k)
                if (s_ok[k]) *reinterpret_cast<float4*>(&buf[pb ^ 1][0][0] + s_off[k]) = p[k];
        }
        __syncthreads();
    }

    // relu + per-thread reduce over 2 rows x 4 cols
    float vals[8];
#pragma unroll
    for (int c = 0; c < 8; ++c) vals[c] = 0.f;
    if (active) {
#pragma unroll
        for (int c = 0; c < 4; ++c) {
            float s0 = 0.f;
#pragma unroll
            for (int v = 0; v < 4; ++v) s0 += fmaxf(accA[c][v], 0.f) + fmaxf(accB[c][v], 0.f);
            vals[c] = s0;
            float m0 = 0.f;
#pragma unroll
            for (int v = 0; v < 4; ++v) m0 = fmaxf(m0, fmaxf(fmaxf(accA[c + 4][v], 0.f), fmaxf(accB[c + 4][v], 0.f)));
            vals[c + 4] = m0;
        }
    }

#pragma unroll
    for (int off = 32; off > 0; off >>= 1) {
#pragma unroll
        for (int c = 0; c < 4; ++c) vals[c] += __shfl_xor(vals[c], off, 64);
#pragma unroll
        for (int c = 4; c < 8; ++c) vals[c] = fmaxf(vals[c], __shfl_xor(vals[c], off, 64));
    }
    const int wv = tid >> 6;
    if (lane == 0) {
#pragma unroll
        for (int c = 0; c < 8; ++c) wred[wv][c] = vals[c];
    }
    __syncthreads();
    if (tid < 8) {
        const float a0 = wred[0][tid], a1 = wred[1][tid], a2 = wred[2][tid], a3 = wred[3][tid];
        const float r = (tid < 8 && tid >= 4) ? fmaxf(fmaxf(a0, a1), fmaxf(a2, a3)) : (a0 + a1 + a2 + a3);
        partials[((size_t)b * 125 + blockIdx.x) * 8 + tid] = r;
    }
}

// ---------------- K7: reduce partials -> topo[b][8] ----------------
__global__ __launch_bounds__(256) void k_topo(const float* __restrict__ partials,
                                              float* __restrict__ topo) {
    const int b = blockIdx.x;
    const int tid = threadIdx.x;
    const int c = tid & 7;
    const int g = tid >> 3;  // 32 groups
    float vs = 0.f, vm = 0.f;
    for (int rp = g; rp < 125; rp += 32) {
        const float v = partials[((size_t)b * 125 + rp) * 8 + c];
        vs += v;
        vm = fmaxf(vm, v);
    }
    __shared__ float red[256];
    red[tid] = (c < 4) ? vs : vm;
    __syncthreads();
    for (int s = 16; s > 0; s >>= 1) {
        if (g < s) {
            const float a = red[tid];
            const float bv = red[tid + s * 8];
            red[tid] = (c < 4) ? (a + bv) : fmaxf(a, bv);
        }
        __syncthreads();
    }
    if (tid < 8) topo[b * 8 + tid] = (tid < 4) ? red[tid] * (1.f / (NN * (float)NN)) : red[tid];
}

// ---------------- K8: assemble output ----------------
__global__ __launch_bounds__(64) void k_out(const float* __restrict__ x,
                                            const float* __restrict__ y1,
                                            const float* __restrict__ y2,
                                            const float* __restrict__ W,
                                            const float* __restrict__ biasN,
                                            const float* __restrict__ wws,
                                            const float* __restrict__ wwt,
                                            const float* __restrict__ M,
                                            const float* __restrict__ wsum,
                                            const float* __restrict__ topo,
                                            float* __restrict__ out) {
    const int bn = blockIdx.x;
    const int b = bn / NN;
    const int n = bn - b * NN;
    const int o = threadIdx.x;
    float val;
    if (o < 48) {
        val = x[bn] * W[n * 144 + o] + y1[bn] * W[n * 144 + 48 + o] + y2[bn] * W[n * 144 + 96 + o];
    } else if (o < 56) {
        const int oo = o - 48;
        val = M[bn] * wws[n * 8 + oo] * topo[b * 8 + oo];
    } else {
        const int oo = o - 56;
        val = wsum[bn] * wwt[n * 8 + oo];
    }
    out[(size_t)bn * 64 + o] = val + biasN[n * 64 + o];
}

extern "C" void kernel_launch(void* const* d_in, const int* in_sizes, int n_in,
                              void* d_out, int out_size, void* d_ws, size_t ws_size,
                              hipStream_t stream) {
    const float* x    = (const float*)d_in[0];
    const float* xw   = (const float*)d_in[1];
    const float* E    = (const float*)d_in[2];
    const float* MPG  = (const float*)d_in[4];
    const int*   bidx = (const int*)d_in[5];
    const int*   stay = (const int*)d_in[7];
    const int*   jump = (const int*)d_in[8];
    const float* wp   = (const float*)d_in[9];
    const float* wwsp = (const float*)d_in[10];
    const float* wwtp = (const float*)d_in[11];
    const float* bp   = (const float*)d_in[12];
    const float* Tp   = (const float*)d_in[13];
    const float* cmw  = (const float*)d_in[14];
    const float* cmb  = (const float*)d_in[15];
    const float* cxw  = (const float*)d_in[16];
    const float* cxb  = (const float*)d_in[17];
    float* out = (float*)d_out;

    float* w = (float*)d_ws;
    float* S     = w;               // 250000
    float* y1    = S + 250000;      // 16000
    float* y2    = y1 + 16000;      // 16000
    float* W     = y2 + 16000;      // 72000
    float* biasN = W + 72000;       // 32000
    float* wws   = biasN + 32000;   // 4000
    float* wwt   = wws + 4000;      // 4000
    float* M     = wwt + 4000;      // 16000
    float* wsum  = M + 16000;       // 16000
    float* parts = wsum + 16000;    // 64000
    float* topo  = parts + 64000;   // 256

    k_softmaxS<<<NN, 256, 0, stream>>>(E, stay, S);
    k_matvecS<<<dim3(125, BB), 256, 0, stream>>>(S, x, y1);
    k_matvecS<<<dim3(125, BB), 256, 0, stream>>>(S, y1, y2);
    k_smallpre<<<NN, 256, 0, stream>>>(E, wp, bp, wwsp, wwtp, W, biasN, wws, wwt);
    k_Mwsum<<<dim3(4, BB), 128, 0, stream>>>(xw, S, bidx, jump, Tp, M, wsum);
    k_conv<<<dim3(125, BB), 256, 0, stream>>>(MPG, cmw, cmb, cxw, cxb, parts);
    k_topo<<<BB, 256, 0, stream>>>(parts, topo);
    k_out<<<BB * NN, 64, 0, stream>>>(x, y1, y2, W, biasN, wws, wwt, M, wsum, topo, out);
}

// Round 4
// 261.111 us; speedup vs baseline: 1.1992x; 1.1992x over previous
//
#include <hip/hip_runtime.h>

#define NN 500
#define BB 32
#define TT 12
#define EMB 10

// ---------------- K1: S = softmax(relu(E E^T) with diag=stay), rows ----------------
__global__ __launch_bounds__(256) void k_softmaxS(const float* __restrict__ E,
                                                  const int* __restrict__ stay,
                                                  float* __restrict__ S) {
    const int i = blockIdx.x;
    const int tid = threadIdx.x;
    __shared__ float row[NN];
    __shared__ float red[256];
    float ei[EMB];
#pragma unroll
    for (int d = 0; d < EMB; ++d) ei[d] = E[i * EMB + d];
    const float stayf = (float)stay[0];

    float lmax = -1e30f;
    for (int j = tid; j < NN; j += 256) {
        float acc = 0.f;
#pragma unroll
        for (int d = 0; d < EMB; ++d) acc += ei[d] * E[j * EMB + d];
        float v = acc > 0.f ? acc : 0.f;
        if (j == i) v = stayf;
        row[j] = v;
        lmax = fmaxf(lmax, v);
    }
    red[tid] = lmax;
    __syncthreads();
    for (int s = 128; s > 0; s >>= 1) {
        if (tid < s) red[tid] = fmaxf(red[tid], red[tid + s]);
        __syncthreads();
    }
    const float rmax = red[0];
    __syncthreads();

    float lsum = 0.f;
    for (int j = tid; j < NN; j += 256) {
        float e = __expf(row[j] - rmax);
        row[j] = e;
        lsum += e;
    }
    red[tid] = lsum;
    __syncthreads();
    for (int s = 128; s > 0; s >>= 1) {
        if (tid < s) red[tid] += red[tid + s];
        __syncthreads();
    }
    const float inv = 1.0f / red[0];
    for (int j = tid; j < NN; j += 256) S[i * NN + j] = row[j] * inv;
}

// ---------------- K2/K3: y[b,n] = sum_m S[n,m] * xin[b,m] (wave per row) ----------------
__global__ __launch_bounds__(256) void k_matvecS(const float* __restrict__ S,
                                                 const float* __restrict__ xin,
                                                 float* __restrict__ yout) {
    const int b = blockIdx.y;
    const int w = threadIdx.x >> 6;
    const int lane = threadIdx.x & 63;
    const int n = blockIdx.x * 4 + w;
    const float* xb = xin + b * NN;
    const float* Sr = S + n * NN;
    float acc = 0.f;
    for (int m = lane; m < NN; m += 64) acc += Sr[m] * xb[m];
#pragma unroll
    for (int off = 32; off > 0; off >>= 1) acc += __shfl_down(acc, off, 64);
    if (lane == 0) yout[b * NN + n] = acc;
}

// ---------------- K4: per-node small weights from embeddings ----------------
__global__ __launch_bounds__(256) void k_smallpre(const float* __restrict__ E,
                                                  const float* __restrict__ wp,
                                                  const float* __restrict__ bp,
                                                  const float* __restrict__ wwsp,
                                                  const float* __restrict__ wwtp,
                                                  float* __restrict__ W,
                                                  float* __restrict__ biasN,
                                                  float* __restrict__ wws,
                                                  float* __restrict__ wwt) {
    const int n = blockIdx.x;
    const int tid = threadIdx.x;
    __shared__ float e[EMB];
    if (tid < EMB) e[tid] = E[n * EMB + tid];
    __syncthreads();
    if (tid < 144) {
        float acc = 0.f;
#pragma unroll
        for (int d = 0; d < EMB; ++d) acc += e[d] * wp[d * 144 + tid];
        W[n * 144 + tid] = acc;
    } else if (tid < 208) {
        const int o = tid - 144;
        float acc = 0.f;
#pragma unroll
        for (int d = 0; d < EMB; ++d) acc += e[d] * bp[d * 64 + o];
        biasN[n * 64 + o] = acc;
    } else if (tid < 216) {
        const int o = tid - 208;
        float acc = 0.f;
#pragma unroll
        for (int d = 0; d < EMB; ++d) acc += e[d] * wwsp[d * 8 + o];
        wws[n * 8 + o] = acc;
    } else if (tid < 224) {
        const int o = tid - 216;
        float acc = 0.f;
#pragma unroll
        for (int d = 0; d < EMB; ++d) acc += e[d] * wwtp[d * 8 + o];
        wwt[n * 8 + o] = acc;
    }
}

// ---------------- K5: M[b,n] = mean_f xws, wsum[b,n] = sum_t xw[b,t,n]*T[t] ----------------
__global__ __launch_bounds__(128) void k_Mwsum(const float* __restrict__ xwin,
                                               const float* __restrict__ S,
                                               const int* __restrict__ bidx,
                                               const int* __restrict__ jumpc,
                                               const float* __restrict__ Tp,
                                               float* __restrict__ M,
                                               float* __restrict__ wsum) {
    const int b = blockIdx.y;
    const int n0 = blockIdx.x * 125;
    const int tid = threadIdx.x;
    __shared__ float xsf[NN];
    __shared__ float Tl[TT];
    const int t0 = bidx[0], t1 = bidx[1], t2 = bidx[2];
    if (tid < TT) Tl[tid] = Tp[tid];
    const float* xb = xwin + (size_t)b * TT * NN;
    for (int m = tid; m < NN; m += 128)
        xsf[m] = xb[t0 * NN + m] + xb[t1 * NN + m] + xb[t2 * NN + m];
    __syncthreads();
    if (tid < 125) {
        const int n = n0 + tid;
        float ws_ = 0.f;
#pragma unroll
        for (int t = 0; t < TT; ++t) ws_ += xb[t * NN + n] * Tl[t];
        const float jc = (float)jumpc[0];
        const float jterm = jc * (2.f * xb[t0 * NN + n] + xb[t1 * NN + n]);
        float acc = 0.f;
        for (int m = 0; m < NN; ++m) acc += xsf[m] * S[m * NN + n];
        M[b * NN + n] = (acc + jterm) * (1.f / 3.f);
        wsum[b * NN + n] = ws_;
    }
}

// ---------------- K6: fused dual conv; LDS dbuf for aligned reads, GLOBAL prefetched edges ----------------
__global__ __launch_bounds__(256, 4) void k_conv(const float* __restrict__ MPG,
                                                 const float* __restrict__ wm,
                                                 const float* __restrict__ bmv,
                                                 const float* __restrict__ wx,
                                                 const float* __restrict__ bxv,
                                                 float* __restrict__ partials) {
    const int b = blockIdx.y;
    const int r0 = blockIdx.x * 2;   // output rows r0, r0+1
    const int tid = threadIdx.x;
    const int ry = tid >> 7;         // 0..1 -> output row r0+ry
    const int tx = tid & 127;
    const int lane = tid & 63;
    const int c0 = tx * 4;
    const bool active = (tx < 125);

    __shared__ float buf[2][4 * NN];   // dbuf x 4 staged rows x 500 (unpadded)
    __shared__ float wred[4][8];

    const float* base_b = MPG + (size_t)b * (TT * NN * NN);

    // staging: 4 rows x 125 float4 = 500 float4 per tile; thread handles f = tid, tid+256
    int s_off[2];
    int g_off[2];
    bool s_ok[2], g_ok[2];
#pragma unroll
    for (int k = 0; k < 2; ++k) {
        const int f = tid + k * 256;
        const int row = f / 125;
        const int col = (f - row * 125) * 4;
        s_ok[k] = (f < 500);
        s_off[k] = row * NN + col;
        const int grow = r0 - 1 + row;
        g_ok[k] = s_ok[k] && (grow >= 0) && (grow < NN);
        g_off[k] = grow * NN + col;
    }

    // edge metadata: for kh, global row gr = r0+ry+kh-1; left col c0-1, right col c0+4
    bool lok[3], rok[3];
    int loff[3], roff[3];
#pragma unroll
    for (int kh = 0; kh < 3; ++kh) {
        const int gr = r0 + ry + kh - 1;
        const bool rv = (gr >= 0) && (gr < NN);
        lok[kh] = active && rv && (c0 > 0);
        rok[kh] = active && rv && (c0 + 4 < NN);
        loff[kh] = gr * NN + c0 - 1;
        roff[kh] = gr * NN + c0 + 4;
    }

    float acc[8][4];
#pragma unroll
    for (int c = 0; c < 4; ++c) {
        const float bm = bmv[c];
        const float bx = bxv[c];
#pragma unroll
        for (int v = 0; v < 4; ++v) {
            acc[c][v] = bm;
            acc[c + 4][v] = bx;
        }
    }

    float4 p[2];
    float eL[3], eR[3], nL[3], nR[3];

    // prologue: stage t=0 + edges t=0
#pragma unroll
    for (int k = 0; k < 2; ++k) {
        p[k] = make_float4(0.f, 0.f, 0.f, 0.f);
        if (g_ok[k]) p[k] = *reinterpret_cast<const float4*>(base_b + g_off[k]);
    }
#pragma unroll
    for (int kh = 0; kh < 3; ++kh) {
        eL[kh] = lok[kh] ? base_b[loff[kh]] : 0.f;
        eR[kh] = rok[kh] ? base_b[roff[kh]] : 0.f;
    }
#pragma unroll
    for (int k = 0; k < 2; ++k)
        if (s_ok[k]) *reinterpret_cast<float4*>(&buf[0][0] + s_off[k]) = p[k];
    __syncthreads();

    for (int t = 0; t < TT; ++t) {
        const int pb = t & 1;
        const bool pf = (t + 1) < TT;
        // issue next-tile global loads early (hidden under compute)
        if (pf) {
            const float* tb = base_b + (size_t)(t + 1) * NN * NN;
#pragma unroll
            for (int k = 0; k < 2; ++k) {
                p[k] = make_float4(0.f, 0.f, 0.f, 0.f);
                if (g_ok[k]) p[k] = *reinterpret_cast<const float4*>(tb + g_off[k]);
            }
#pragma unroll
            for (int kh = 0; kh < 3; ++kh) {
                nL[kh] = lok[kh] ? tb[loff[kh]] : 0.f;
                nR[kh] = rok[kh] ? tb[roff[kh]] : 0.f;
            }
        }

        // compute tile t from buf[pb] + edge regs
        const float* wmt = wm + t * 9;
        const float* wxt = wx + t * 9;
#pragma unroll
        for (int kh = 0; kh < 3; ++kh) {
            const float* lr = &buf[pb][(ry + kh) * NN];
            const float4 R = *reinterpret_cast<const float4*>(&lr[c0]);
            const float in[6] = {eL[kh], R.x, R.y, R.z, R.w, eR[kh]};
#pragma unroll
            for (int c = 0; c < 4; ++c) {
                const float* wm9 = wmt + c * (TT * 9) + kh * 3;
                const float* wx9 = wxt + c * (TT * 9) + kh * 3;
#pragma unroll
                for (int kw = 0; kw < 3; ++kw) {
                    const float w1 = wm9[kw];
                    const float w2 = wx9[kw];
#pragma unroll
                    for (int v = 0; v < 4; ++v) {
                        acc[c][v] = fmaf(in[v + kw], w1, acc[c][v]);
                        acc[c + 4][v] = fmaf(in[v + kw], w2, acc[c + 4][v]);
                    }
                }
            }
        }

        // write next tile into the other buffer, then single barrier
        if (pf) {
#pragma unroll
            for (int k = 0; k < 2; ++k)
                if (s_ok[k]) *reinterpret_cast<float4*>(&buf[pb ^ 1][0] + s_off[k]) = p[k];
        }
        __syncthreads();
#pragma unroll
        for (int kh = 0; kh < 3; ++kh) {
            eL[kh] = nL[kh];
            eR[kh] = nR[kh];
        }
    }

    // relu + per-thread reduce
    float vals[8];
#pragma unroll
    for (int c = 0; c < 8; ++c) vals[c] = 0.f;
    if (active) {
#pragma unroll
        for (int c = 0; c < 4; ++c) {
            float s0 = 0.f;
#pragma unroll
            for (int v = 0; v < 4; ++v) s0 += fmaxf(acc[c][v], 0.f);
            vals[c] = s0;
            float m0 = 0.f;
#pragma unroll
            for (int v = 0; v < 4; ++v) m0 = fmaxf(m0, fmaxf(acc[c + 4][v], 0.f));
            vals[c + 4] = m0;
        }
    }

    // wave butterfly reduce
#pragma unroll
    for (int off = 32; off > 0; off >>= 1) {
#pragma unroll
        for (int c = 0; c < 4; ++c) vals[c] += __shfl_xor(vals[c], off, 64);
#pragma unroll
        for (int c = 4; c < 8; ++c) vals[c] = fmaxf(vals[c], __shfl_xor(vals[c], off, 64));
    }
    const int wv = tid >> 6;
    if (lane == 0) {
#pragma unroll
        for (int c = 0; c < 8; ++c) wred[wv][c] = vals[c];
    }
    __syncthreads();
    if (tid < 8) {
        const float a0 = wred[0][tid], a1 = wred[1][tid], a2 = wred[2][tid], a3 = wred[3][tid];
        const float r = (tid < 4) ? (a0 + a1 + a2 + a3) : fmaxf(fmaxf(a0, a1), fmaxf(a2, a3));
        partials[((size_t)b * 250 + blockIdx.x) * 8 + tid] = r;
    }
}

// ---------------- K7: reduce partials -> topo[b][8] ----------------
__global__ __launch_bounds__(256) void k_topo(const float* __restrict__ partials,
                                              float* __restrict__ topo) {
    const int b = blockIdx.x;
    const int tid = threadIdx.x;
    const int c = tid & 7;
    const int g = tid >> 3;  // 32 groups
    float vs = 0.f, vm = 0.f;
    for (int rp = g; rp < 250; rp += 32) {
        const float v = partials[((size_t)b * 250 + rp) * 8 + c];
        vs += v;
        vm = fmaxf(vm, v);
    }
    __shared__ float red[256];
    red[tid] = (c < 4) ? vs : vm;
    __syncthreads();
    for (int s = 16; s > 0; s >>= 1) {
        if (g < s) {
            const float a = red[tid];
            const float bv = red[tid + s * 8];
            red[tid] = (c < 4) ? (a + bv) : fmaxf(a, bv);
        }
        __syncthreads();
    }
    if (tid < 8) topo[b * 8 + tid] = (tid < 4) ? red[tid] * (1.f / (NN * (float)NN)) : red[tid];
}

// ---------------- K8: assemble output ----------------
__global__ __launch_bounds__(64) void k_out(const float* __restrict__ x,
                                            const float* __restrict__ y1,
                                            const float* __restrict__ y2,
                                            const float* __restrict__ W,
                                            const float* __restrict__ biasN,
                                            const float* __restrict__ wws,
                                            const float* __restrict__ wwt,
                                            const float* __restrict__ M,
                                            const float* __restrict__ wsum,
                                            const float* __restrict__ topo,
                                            float* __restrict__ out) {
    const int bn = blockIdx.x;
    const int b = bn / NN;
    const int n = bn - b * NN;
    const int o = threadIdx.x;
    float val;
    if (o < 48) {
        val = x[bn] * W[n * 144 + o] + y1[bn] * W[n * 144 + 48 + o] + y2[bn] * W[n * 144 + 96 + o];
    } else if (o < 56) {
        const int oo = o - 48;
        val = M[bn] * wws[n * 8 + oo] * topo[b * 8 + oo];
    } else {
        const int oo = o - 56;
        val = wsum[bn] * wwt[n * 8 + oo];
    }
    out[(size_t)bn * 64 + o] = val + biasN[n * 64 + o];
}

extern "C" void kernel_launch(void* const* d_in, const int* in_sizes, int n_in,
                              void* d_out, int out_size, void* d_ws, size_t ws_size,
                              hipStream_t stream) {
    const float* x    = (const float*)d_in[0];
    const float* xw   = (const float*)d_in[1];
    const float* E    = (const float*)d_in[2];
    const float* MPG  = (const float*)d_in[4];
    const int*   bidx = (const int*)d_in[5];
    const int*   stay = (const int*)d_in[7];
    const int*   jump = (const int*)d_in[8];
    const float* wp   = (const float*)d_in[9];
    const float* wwsp = (const float*)d_in[10];
    const float* wwtp = (const float*)d_in[11];
    const float* bp   = (const float*)d_in[12];
    const float* Tp   = (const float*)d_in[13];
    const float* cmw  = (const float*)d_in[14];
    const float* cmb  = (const float*)d_in[15];
    const float* cxw  = (const float*)d_in[16];
    const float* cxb  = (const float*)d_in[17];
    float* out = (float*)d_out;

    float* w = (float*)d_ws;
    float* S     = w;               // 250000
    float* y1    = S + 250000;      // 16000
    float* y2    = y1 + 16000;      // 16000
    float* W     = y2 + 16000;      // 72000
    float* biasN = W + 72000;       // 32000
    float* wws   = biasN + 32000;   // 4000
    float* wwt   = wws + 4000;      // 4000
    float* M     = wwt + 4000;      // 16000
    float* wsum  = M + 16000;       // 16000
    float* parts = wsum + 16000;    // 64000
    float* topo  = parts + 64000;   // 256

    k_softmaxS<<<NN, 256, 0, stream>>>(E, stay, S);
    k_matvecS<<<dim3(125, BB), 256, 0, stream>>>(S, x, y1);
    k_matvecS<<<dim3(125, BB), 256, 0, stream>>>(S, y1, y2);
    k_smallpre<<<NN, 256, 0, stream>>>(E, wp, bp, wwsp, wwtp, W, biasN, wws, wwt);
    k_Mwsum<<<dim3(4, BB), 128, 0, stream>>>(xw, S, bidx, jump, Tp, M, wsum);
    k_conv<<<dim3(250, BB), 256, 0, stream>>>(MPG, cmw, cmb, cxw, cxb, parts);
    k_topo<<<BB, 256, 0, stream>>>(parts, topo);
    k_out<<<BB * NN, 64, 0, stream>>>(x, y1, y2, W, biasN, wws, wwt, M, wsum, topo, out);
}

// Round 5
// 251.442 us; speedup vs baseline: 1.2453x; 1.0385x over previous
//
#include <hip/hip_runtime.h>

#define NN 500
#define BB 32
#define TT 12
#define EMB 10

// ---------------- K1: S = softmax(relu(E E^T) with diag=stay), rows ----------------
__global__ __launch_bounds__(256) void k_softmaxS(const float* __restrict__ E,
                                                  const int* __restrict__ stay,
                                                  float* __restrict__ S) {
    const int i = blockIdx.x;
    const int tid = threadIdx.x;
    __shared__ float row[NN];
    __shared__ float red[256];
    float ei[EMB];
#pragma unroll
    for (int d = 0; d < EMB; ++d) ei[d] = E[i * EMB + d];
    const float stayf = (float)stay[0];

    float lmax = -1e30f;
    for (int j = tid; j < NN; j += 256) {
        float acc = 0.f;
#pragma unroll
        for (int d = 0; d < EMB; ++d) acc += ei[d] * E[j * EMB + d];
        float v = acc > 0.f ? acc : 0.f;
        if (j == i) v = stayf;
        row[j] = v;
        lmax = fmaxf(lmax, v);
    }
    red[tid] = lmax;
    __syncthreads();
    for (int s = 128; s > 0; s >>= 1) {
        if (tid < s) red[tid] = fmaxf(red[tid], red[tid + s]);
        __syncthreads();
    }
    const float rmax = red[0];
    __syncthreads();

    float lsum = 0.f;
    for (int j = tid; j < NN; j += 256) {
        float e = __expf(row[j] - rmax);
        row[j] = e;
        lsum += e;
    }
    red[tid] = lsum;
    __syncthreads();
    for (int s = 128; s > 0; s >>= 1) {
        if (tid < s) red[tid] += red[tid + s];
        __syncthreads();
    }
    const float inv = 1.0f / red[0];
    for (int j = tid; j < NN; j += 256) S[i * NN + j] = row[j] * inv;
}

// ---------------- K2/K3: y[b,n] = sum_m S[n,m] * xin[b,m] (wave per row) ----------------
__global__ __launch_bounds__(256) void k_matvecS(const float* __restrict__ S,
                                                 const float* __restrict__ xin,
                                                 float* __restrict__ yout) {
    const int b = blockIdx.y;
    const int w = threadIdx.x >> 6;
    const int lane = threadIdx.x & 63;
    const int n = blockIdx.x * 4 + w;
    const float* xb = xin + b * NN;
    const float* Sr = S + n * NN;
    float acc = 0.f;
    for (int m = lane; m < NN; m += 64) acc += Sr[m] * xb[m];
#pragma unroll
    for (int off = 32; off > 0; off >>= 1) acc += __shfl_down(acc, off, 64);
    if (lane == 0) yout[b * NN + n] = acc;
}

// ---------------- K4: per-node small weights from embeddings ----------------
__global__ __launch_bounds__(256) void k_smallpre(const float* __restrict__ E,
                                                  const float* __restrict__ wp,
                                                  const float* __restrict__ bp,
                                                  const float* __restrict__ wwsp,
                                                  const float* __restrict__ wwtp,
                                                  float* __restrict__ W,
                                                  float* __restrict__ biasN,
                                                  float* __restrict__ wws,
                                                  float* __restrict__ wwt) {
    const int n = blockIdx.x;
    const int tid = threadIdx.x;
    __shared__ float e[EMB];
    if (tid < EMB) e[tid] = E[n * EMB + tid];
    __syncthreads();
    if (tid < 144) {
        float acc = 0.f;
#pragma unroll
        for (int d = 0; d < EMB; ++d) acc += e[d] * wp[d * 144 + tid];
        W[n * 144 + tid] = acc;
    } else if (tid < 208) {
        const int o = tid - 144;
        float acc = 0.f;
#pragma unroll
        for (int d = 0; d < EMB; ++d) acc += e[d] * bp[d * 64 + o];
        biasN[n * 64 + o] = acc;
    } else if (tid < 216) {
        const int o = tid - 208;
        float acc = 0.f;
#pragma unroll
        for (int d = 0; d < EMB; ++d) acc += e[d] * wwsp[d * 8 + o];
        wws[n * 8 + o] = acc;
    } else if (tid < 224) {
        const int o = tid - 216;
        float acc = 0.f;
#pragma unroll
        for (int d = 0; d < EMB; ++d) acc += e[d] * wwtp[d * 8 + o];
        wwt[n * 8 + o] = acc;
    }
}

// ---------------- K5: M[b,n] = mean_f xws, wsum[b,n] = sum_t xw[b,t,n]*T[t] ----------------
__global__ __launch_bounds__(128) void k_Mwsum(const float* __restrict__ xwin,
                                               const float* __restrict__ S,
                                               const int* __restrict__ bidx,
                                               const int* __restrict__ jumpc,
                                               const float* __restrict__ Tp,
                                               float* __restrict__ M,
                                               float* __restrict__ wsum) {
    const int b = blockIdx.y;
    const int n0 = blockIdx.x * 125;
    const int tid = threadIdx.x;
    __shared__ float xsf[NN];
    __shared__ float Tl[TT];
    const int t0 = bidx[0], t1 = bidx[1], t2 = bidx[2];
    if (tid < TT) Tl[tid] = Tp[tid];
    const float* xb = xwin + (size_t)b * TT * NN;
    for (int m = tid; m < NN; m += 128)
        xsf[m] = xb[t0 * NN + m] + xb[t1 * NN + m] + xb[t2 * NN + m];
    __syncthreads();
    if (tid < 125) {
        const int n = n0 + tid;
        float ws_ = 0.f;
#pragma unroll
        for (int t = 0; t < TT; ++t) ws_ += xb[t * NN + n] * Tl[t];
        const float jc = (float)jumpc[0];
        const float jterm = jc * (2.f * xb[t0 * NN + n] + xb[t1 * NN + n]);
        float acc = 0.f;
        for (int m = 0; m < NN; ++m) acc += xsf[m] * S[m * NN + n];
        M[b * NN + n] = (acc + jterm) * (1.f / 3.f);
        wsum[b * NN + n] = ws_;
    }
}

// ---------------- K6: fused dual conv — no LDS, L1-served aligned loads, SGPR row bases ----------------
// Thread (ry=tid>>7, tx=tid&127) computes output row r0+ry, cols {4tx+1..4tx+3, tx<124 ? 4tx+4 : 0}.
// Inputs for those cols: aligned float4 at col 4tx (F1) and at (tx==124 ? 0 : 4tx+4) (F2).
// Row out-of-range -> wave-uniform pointer swap to a zeroed scratch row (zrow).
__global__ __launch_bounds__(256, 4) void k_conv(const float* __restrict__ MPG,
                                                 const float* __restrict__ wm,
                                                 const float* __restrict__ bmv,
                                                 const float* __restrict__ wx,
                                                 const float* __restrict__ bxv,
                                                 const float* __restrict__ zrow,
                                                 float* __restrict__ partials) {
    const int b = blockIdx.y;
    const int r0 = blockIdx.x * 2;
    const int tid = threadIdx.x;
    const int ry = __builtin_amdgcn_readfirstlane(tid >> 7);  // wave-uniform -> scalar
    const int tx = tid & 127;
    const int lane = tid & 63;
    const bool active = (tx < 125);
    const bool wrap = (tx == 124);

    // wave-uniform (SGPR) row base pointers + per-t byte advances
    const float* rp[3];
    int adv[3];
#pragma unroll
    for (int kh = 0; kh < 3; ++kh) {
        const int gr = r0 + ry - 1 + kh;
        const bool ok = (gr >= 0) && (gr < NN);
        rp[kh] = ok ? (MPG + (size_t)b * (TT * NN * NN) + (size_t)gr * NN) : zrow;
        adv[kh] = ok ? (NN * NN * 4) : 0;
    }
    // per-lane 32-bit voffsets (bytes)
    const int baseA = active ? tx * 16 : 0;
    const int baseB = (active && !wrap) ? tx * 16 + 16 : 0;
    int voffA[3], voffB[3];
#pragma unroll
    for (int kh = 0; kh < 3; ++kh) { voffA[kh] = baseA; voffB[kh] = baseB; }

    float acc[8][4];
#pragma unroll
    for (int c = 0; c < 4; ++c) {
        const float bm = bmv[c];
        const float bx = bxv[c];
#pragma unroll
        for (int v = 0; v < 4; ++v) {
            acc[c][v] = bm;
            acc[c + 4][v] = bx;
        }
    }

    for (int t = 0; t < TT; ++t) {
        float4 F1[3], F2[3];
#pragma unroll
        for (int kh = 0; kh < 3; ++kh) {
            F1[kh] = *reinterpret_cast<const float4*>(reinterpret_cast<const char*>(rp[kh]) + voffA[kh]);
            F2[kh] = *reinterpret_cast<const float4*>(reinterpret_cast<const char*>(rp[kh]) + voffB[kh]);
        }
        const float* wmt = wm + t * 9;
        const float* wxt = wx + t * 9;
#pragma unroll
        for (int kh = 0; kh < 3; ++kh) {
            const float i0 = F1[kh].x, i1 = F1[kh].y, i2 = F1[kh].z, i3 = F1[kh].w;
            const float i4 = wrap ? 0.f : F2[kh].x;   // col 4tx+4 (0 past right edge)
            const float w30 = wrap ? 0.f : i3;        // window for col j=4tx+4 (or j=0 if wrap)
            const float w31 = F2[kh].x;
            const float w32 = F2[kh].y;
            // windows per output v: v0:(i0,i1,i2) v1:(i1,i2,i3) v2:(i2,i3,i4) v3:(w30,w31,w32)
            const float win[4][3] = {{i0, i1, i2}, {i1, i2, i3}, {i2, i3, i4}, {w30, w31, w32}};
#pragma unroll
            for (int c = 0; c < 4; ++c) {
                const float* wm9 = wmt + c * (TT * 9) + kh * 3;
                const float* wx9 = wxt + c * (TT * 9) + kh * 3;
#pragma unroll
                for (int kw = 0; kw < 3; ++kw) {
                    const float w1 = wm9[kw];
                    const float w2 = wx9[kw];
#pragma unroll
                    for (int v = 0; v < 4; ++v) {
                        acc[c][v] = fmaf(win[v][kw], w1, acc[c][v]);
                        acc[c + 4][v] = fmaf(win[v][kw], w2, acc[c + 4][v]);
                    }
                }
            }
        }
#pragma unroll
        for (int kh = 0; kh < 3; ++kh) { voffA[kh] += adv[kh]; voffB[kh] += adv[kh]; }
    }

    // relu + per-thread reduce (all 4 outputs of an active thread are valid pixels)
    float vals[8];
#pragma unroll
    for (int c = 0; c < 8; ++c) vals[c] = 0.f;
    if (active) {
#pragma unroll
        for (int c = 0; c < 4; ++c) {
            float s0 = 0.f;
#pragma unroll
            for (int v = 0; v < 4; ++v) s0 += fmaxf(acc[c][v], 0.f);
            vals[c] = s0;
            float m0 = 0.f;
#pragma unroll
            for (int v = 0; v < 4; ++v) m0 = fmaxf(m0, fmaxf(acc[c + 4][v], 0.f));
            vals[c + 4] = m0;
        }
    }

    // wave butterfly reduce
#pragma unroll
    for (int off = 32; off > 0; off >>= 1) {
#pragma unroll
        for (int c = 0; c < 4; ++c) vals[c] += __shfl_xor(vals[c], off, 64);
#pragma unroll
        for (int c = 4; c < 8; ++c) vals[c] = fmaxf(vals[c], __shfl_xor(vals[c], off, 64));
    }
    __shared__ float wred[4][8];
    const int wv = tid >> 6;
    if (lane == 0) {
#pragma unroll
        for (int c = 0; c < 8; ++c) wred[wv][c] = vals[c];
    }
    __syncthreads();
    if (tid < 8) {
        const float a0 = wred[0][tid], a1 = wred[1][tid], a2 = wred[2][tid], a3 = wred[3][tid];
        const float r = (tid < 4) ? (a0 + a1 + a2 + a3) : fmaxf(fmaxf(a0, a1), fmaxf(a2, a3));
        partials[((size_t)b * 250 + blockIdx.x) * 8 + tid] = r;
    }
}

// ---------------- K7: reduce partials -> topo[b][8] ----------------
__global__ __launch_bounds__(256) void k_topo(const float* __restrict__ partials,
                                              float* __restrict__ topo) {
    const int b = blockIdx.x;
    const int tid = threadIdx.x;
    const int c = tid & 7;
    const int g = tid >> 3;  // 32 groups
    float vs = 0.f, vm = 0.f;
    for (int rp = g; rp < 250; rp += 32) {
        const float v = partials[((size_t)b * 250 + rp) * 8 + c];
        vs += v;
        vm = fmaxf(vm, v);
    }
    __shared__ float red[256];
    red[tid] = (c < 4) ? vs : vm;
    __syncthreads();
    for (int s = 16; s > 0; s >>= 1) {
        if (g < s) {
            const float a = red[tid];
            const float bv = red[tid + s * 8];
            red[tid] = (c < 4) ? (a + bv) : fmaxf(a, bv);
        }
        __syncthreads();
    }
    if (tid < 8) topo[b * 8 + tid] = (tid < 4) ? red[tid] * (1.f / (NN * (float)NN)) : red[tid];
}

// ---------------- K8: assemble output ----------------
__global__ __launch_bounds__(64) void k_out(const float* __restrict__ x,
                                            const float* __restrict__ y1,
                                            const float* __restrict__ y2,
                                            const float* __restrict__ W,
                                            const float* __restrict__ biasN,
                                            const float* __restrict__ wws,
                                            const float* __restrict__ wwt,
                                            const float* __restrict__ M,
                                            const float* __restrict__ wsum,
                                            const float* __restrict__ topo,
                                            float* __restrict__ out) {
    const int bn = blockIdx.x;
    const int b = bn / NN;
    const int n = bn - b * NN;
    const int o = threadIdx.x;
    float val;
    if (o < 48) {
        val = x[bn] * W[n * 144 + o] + y1[bn] * W[n * 144 + 48 + o] + y2[bn] * W[n * 144 + 96 + o];
    } else if (o < 56) {
        const int oo = o - 48;
        val = M[bn] * wws[n * 8 + oo] * topo[b * 8 + oo];
    } else {
        const int oo = o - 56;
        val = wsum[bn] * wwt[n * 8 + oo];
    }
    out[(size_t)bn * 64 + o] = val + biasN[n * 64 + o];
}

extern "C" void kernel_launch(void* const* d_in, const int* in_sizes, int n_in,
                              void* d_out, int out_size, void* d_ws, size_t ws_size,
                              hipStream_t stream) {
    const float* x    = (const float*)d_in[0];
    const float* xw   = (const float*)d_in[1];
    const float* E    = (const float*)d_in[2];
    const float* MPG  = (const float*)d_in[4];
    const int*   bidx = (const int*)d_in[5];
    const int*   stay = (const int*)d_in[7];
    const int*   jump = (const int*)d_in[8];
    const float* wp   = (const float*)d_in[9];
    const float* wwsp = (const float*)d_in[10];
    const float* wwtp = (const float*)d_in[11];
    const float* bp   = (const float*)d_in[12];
    const float* Tp   = (const float*)d_in[13];
    const float* cmw  = (const float*)d_in[14];
    const float* cmb  = (const float*)d_in[15];
    const float* cxw  = (const float*)d_in[16];
    const float* cxb  = (const float*)d_in[17];
    float* out = (float*)d_out;

    float* w = (float*)d_ws;
    float* S     = w;               // 250000
    float* y1    = S + 250000;      // 16000
    float* y2    = y1 + 16000;      // 16000
    float* W     = y2 + 16000;      // 72000
    float* biasN = W + 72000;       // 32000
    float* wws   = biasN + 32000;   // 4000
    float* wwt   = wws + 4000;      // 4000
    float* M     = wwt + 4000;      // 16000
    float* wsum  = M + 16000;       // 16000
    float* parts = wsum + 16000;    // 64000
    float* topo  = parts + 64000;   // 256
    float* zrow  = topo + 256;      // 640 floats zero page

    hipMemsetAsync(zrow, 0, 640 * sizeof(float), stream);
    k_softmaxS<<<NN, 256, 0, stream>>>(E, stay, S);
    k_matvecS<<<dim3(125, BB), 256, 0, stream>>>(S, x, y1);
    k_matvecS<<<dim3(125, BB), 256, 0, stream>>>(S, y1, y2);
    k_smallpre<<<NN, 256, 0, stream>>>(E, wp, bp, wwsp, wwtp, W, biasN, wws, wwt);
    k_Mwsum<<<dim3(4, BB), 128, 0, stream>>>(xw, S, bidx, jump, Tp, M, wsum);
    k_conv<<<dim3(250, BB), 256, 0, stream>>>(MPG, cmw, cmb, cxw, cxb, zrow, parts);
    k_topo<<<BB, 256, 0, stream>>>(parts, topo);
    k_out<<<BB * NN, 64, 0, stream>>>(x, y1, y2, W, biasN, wws, wwt, M, wsum, topo, out);
}

// Round 6
// 232.977 us; speedup vs baseline: 1.3440x; 1.0793x over previous
//
#include <hip/hip_runtime.h>

#define NN 500
#define BB 32
#define TT 12
#define EMB 10

// ---------------- K1: S = softmax(relu(E E^T) with diag=stay), rows ----------------
__global__ __launch_bounds__(256) void k_softmaxS(const float* __restrict__ E,
                                                  const int* __restrict__ stay,
                                                  float* __restrict__ S) {
    const int i = blockIdx.x;
    const int tid = threadIdx.x;
    __shared__ float row[NN];
    __shared__ float red[256];
    float ei[EMB];
#pragma unroll
    for (int d = 0; d < EMB; ++d) ei[d] = E[i * EMB + d];
    const float stayf = (float)stay[0];

    float lmax = -1e30f;
    for (int j = tid; j < NN; j += 256) {
        float acc = 0.f;
#pragma unroll
        for (int d = 0; d < EMB; ++d) acc += ei[d] * E[j * EMB + d];
        float v = acc > 0.f ? acc : 0.f;
        if (j == i) v = stayf;
        row[j] = v;
        lmax = fmaxf(lmax, v);
    }
    red[tid] = lmax;
    __syncthreads();
    for (int s = 128; s > 0; s >>= 1) {
        if (tid < s) red[tid] = fmaxf(red[tid], red[tid + s]);
        __syncthreads();
    }
    const float rmax = red[0];
    __syncthreads();

    float lsum = 0.f;
    for (int j = tid; j < NN; j += 256) {
        float e = __expf(row[j] - rmax);
        row[j] = e;
        lsum += e;
    }
    red[tid] = lsum;
    __syncthreads();
    for (int s = 128; s > 0; s >>= 1) {
        if (tid < s) red[tid] += red[tid + s];
        __syncthreads();
    }
    const float inv = 1.0f / red[0];
    for (int j = tid; j < NN; j += 256) S[i * NN + j] = row[j] * inv;
}

// ---------------- K2/K3: y[b,n] = sum_m S[n,m] * xin[b,m] (wave per row) ----------------
__global__ __launch_bounds__(256) void k_matvecS(const float* __restrict__ S,
                                                 const float* __restrict__ xin,
                                                 float* __restrict__ yout) {
    const int b = blockIdx.y;
    const int w = threadIdx.x >> 6;
    const int lane = threadIdx.x & 63;
    const int n = blockIdx.x * 4 + w;
    const float* xb = xin + b * NN;
    const float* Sr = S + n * NN;
    float acc = 0.f;
    for (int m = lane; m < NN; m += 64) acc += Sr[m] * xb[m];
#pragma unroll
    for (int off = 32; off > 0; off >>= 1) acc += __shfl_down(acc, off, 64);
    if (lane == 0) yout[b * NN + n] = acc;
}

// ---------------- K4: per-node small weights from embeddings ----------------
__global__ __launch_bounds__(256) void k_smallpre(const float* __restrict__ E,
                                                  const float* __restrict__ wp,
                                                  const float* __restrict__ bp,
                                                  const float* __restrict__ wwsp,
                                                  const float* __restrict__ wwtp,
                                                  float* __restrict__ W,
                                                  float* __restrict__ biasN,
                                                  float* __restrict__ wws,
                                                  float* __restrict__ wwt) {
    const int n = blockIdx.x;
    const int tid = threadIdx.x;
    __shared__ float e[EMB];
    if (tid < EMB) e[tid] = E[n * EMB + tid];
    __syncthreads();
    if (tid < 144) {
        float acc = 0.f;
#pragma unroll
        for (int d = 0; d < EMB; ++d) acc += e[d] * wp[d * 144 + tid];
        W[n * 144 + tid] = acc;
    } else if (tid < 208) {
        const int o = tid - 144;
        float acc = 0.f;
#pragma unroll
        for (int d = 0; d < EMB; ++d) acc += e[d] * bp[d * 64 + o];
        biasN[n * 64 + o] = acc;
    } else if (tid < 216) {
        const int o = tid - 208;
        float acc = 0.f;
#pragma unroll
        for (int d = 0; d < EMB; ++d) acc += e[d] * wwsp[d * 8 + o];
        wws[n * 8 + o] = acc;
    } else if (tid < 224) {
        const int o = tid - 216;
        float acc = 0.f;
#pragma unroll
        for (int d = 0; d < EMB; ++d) acc += e[d] * wwtp[d * 8 + o];
        wwt[n * 8 + o] = acc;
    }
}

// ---------------- K5: M[b,n] = mean_f xws, wsum[b,n] = sum_t xw[b,t,n]*T[t] ----------------
__global__ __launch_bounds__(128) void k_Mwsum(const float* __restrict__ xwin,
                                               const float* __restrict__ S,
                                               const int* __restrict__ bidx,
                                               const int* __restrict__ jumpc,
                                               const float* __restrict__ Tp,
                                               float* __restrict__ M,
                                               float* __restrict__ wsum) {
    const int b = blockIdx.y;
    const int n0 = blockIdx.x * 125;
    const int tid = threadIdx.x;
    __shared__ float xsf[NN];
    __shared__ float Tl[TT];
    const int t0 = bidx[0], t1 = bidx[1], t2 = bidx[2];
    if (tid < TT) Tl[tid] = Tp[tid];
    const float* xb = xwin + (size_t)b * TT * NN;
    for (int m = tid; m < NN; m += 128)
        xsf[m] = xb[t0 * NN + m] + xb[t1 * NN + m] + xb[t2 * NN + m];
    __syncthreads();
    if (tid < 125) {
        const int n = n0 + tid;
        float ws_ = 0.f;
#pragma unroll
        for (int t = 0; t < TT; ++t) ws_ += xb[t * NN + n] * Tl[t];
        const float jc = (float)jumpc[0];
        const float jterm = jc * (2.f * xb[t0 * NN + n] + xb[t1 * NN + n]);
        float acc = 0.f;
        for (int m = 0; m < NN; ++m) acc += xsf[m] * S[m * NN + n];
        M[b * NN + n] = (acc + jterm) * (1.f / 3.f);
        wsum[b * NN + n] = ws_;
    }
}

// ---------------- K_wpack: reorder conv weights -> wpack[t][kh][pipe][c][kw] ----------------
__global__ __launch_bounds__(256) void k_wpack(const float* __restrict__ wm,
                                               const float* __restrict__ wx,
                                               float* __restrict__ wpack) {
    const int i = blockIdx.x * 256 + threadIdx.x;
    if (i >= TT * 72) return;
    const int t = i / 72;
    int r = i - t * 72;
    const int kh = r / 24; r -= kh * 24;
    const int pipe = r / 12; r -= pipe * 12;
    const int c = r / 3;
    const int kw = r - c * 3;
    const float* src = pipe ? wx : wm;
    wpack[i] = src[((c * TT + t) * 3 + kh) * 3 + kw];
}

// ---------------- K6 helpers ----------------
__device__ __forceinline__ void conv_load(const float* rp0, const float* rp1, const float* rp2,
                                          int voffA, int voffB, float4 F1[3], float4 F2[3]) {
    F1[0] = *reinterpret_cast<const float4*>(reinterpret_cast<const char*>(rp0) + voffA);
    F2[0] = *reinterpret_cast<const float4*>(reinterpret_cast<const char*>(rp0) + voffB);
    F1[1] = *reinterpret_cast<const float4*>(reinterpret_cast<const char*>(rp1) + voffA);
    F2[1] = *reinterpret_cast<const float4*>(reinterpret_cast<const char*>(rp1) + voffB);
    F1[2] = *reinterpret_cast<const float4*>(reinterpret_cast<const char*>(rp2) + voffA);
    F2[2] = *reinterpret_cast<const float4*>(reinterpret_cast<const char*>(rp2) + voffB);
}

__device__ __forceinline__ void conv_body(const float4 F1[3], const float4 F2[3],
                                          const float* __restrict__ wq, bool wrap,
                                          float acc[8][4]) {
#pragma unroll
    for (int kh = 0; kh < 3; ++kh) {
        float4 w4[6];
#pragma unroll
        for (int j = 0; j < 6; ++j)
            w4[j] = *reinterpret_cast<const float4*>(wq + kh * 24 + j * 4);
        const float wmv[12] = {w4[0].x, w4[0].y, w4[0].z, w4[0].w,
                               w4[1].x, w4[1].y, w4[1].z, w4[1].w,
                               w4[2].x, w4[2].y, w4[2].z, w4[2].w};
        const float wxv[12] = {w4[3].x, w4[3].y, w4[3].z, w4[3].w,
                               w4[4].x, w4[4].y, w4[4].z, w4[4].w,
                               w4[5].x, w4[5].y, w4[5].z, w4[5].w};
        const float i0 = F1[kh].x, i1 = F1[kh].y, i2 = F1[kh].z, i3 = F1[kh].w;
        const float i4 = wrap ? 0.f : F2[kh].x;
        const float w30 = wrap ? 0.f : i3;
        const float w31 = F2[kh].x, w32 = F2[kh].y;
        const float win[4][3] = {{i0, i1, i2}, {i1, i2, i3}, {i2, i3, i4}, {w30, w31, w32}};
#pragma unroll
        for (int c = 0; c < 4; ++c) {
#pragma unroll
            for (int kw = 0; kw < 3; ++kw) {
                const float w1 = wmv[c * 3 + kw];
                const float w2 = wxv[c * 3 + kw];
#pragma unroll
                for (int v = 0; v < 4; ++v) {
                    acc[c][v] = fmaf(win[v][kw], w1, acc[c][v]);
                    acc[c + 4][v] = fmaf(win[v][kw], w2, acc[c + 4][v]);
                }
            }
        }
    }
}

// ---------------- K6: fused dual conv — no LDS, reg ping-pong prefetch, packed weights ----------------
__global__ __launch_bounds__(256, 4) void k_conv(const float* __restrict__ MPG,
                                                 const float* __restrict__ wpack,
                                                 const float* __restrict__ bmv,
                                                 const float* __restrict__ bxv,
                                                 const float* __restrict__ zrow,
                                                 float* __restrict__ partials) {
    const int b = blockIdx.y;
    const int r0 = blockIdx.x * 2;
    const int tid = threadIdx.x;
    const int ry = __builtin_amdgcn_readfirstlane(tid >> 7);  // wave-uniform
    const int tx = tid & 127;
    const int lane = tid & 63;
    const bool active = (tx < 125);
    const bool wrap = (tx == 124);

    // wave-uniform (SGPR) row pointers, advanced by adv floats per t
    const float* rp0;
    const float* rp1;
    const float* rp2;
    int adv0, adv1, adv2;
    {
        const float* base = MPG + (size_t)b * (TT * NN * NN);
        const int g0 = r0 + ry - 1, g1 = r0 + ry, g2 = r0 + ry + 1;
        const bool ok0 = (g0 >= 0), ok2 = (g2 < NN);
        rp0 = ok0 ? base + (size_t)g0 * NN : zrow;
        rp1 = base + (size_t)g1 * NN;
        rp2 = ok2 ? base + (size_t)g2 * NN : zrow;
        adv0 = ok0 ? NN * NN : 0;
        adv1 = NN * NN;
        adv2 = ok2 ? NN * NN : 0;
    }
    const int voffA = active ? tx * 16 : 0;
    const int voffB = (active && !wrap) ? tx * 16 + 16 : 0;

    float acc[8][4];
#pragma unroll
    for (int c = 0; c < 4; ++c) {
        const float bm = bmv[c];
        const float bx = bxv[c];
#pragma unroll
        for (int v = 0; v < 4; ++v) {
            acc[c][v] = bm;
            acc[c + 4][v] = bx;
        }
    }

    float4 Fa1[3], Fa2[3], Fb1[3], Fb2[3];
    conv_load(rp0, rp1, rp2, voffA, voffB, Fa1, Fa2);
    rp0 += adv0; rp1 += adv1; rp2 += adv2;

#pragma unroll 1
    for (int t = 0; t < TT; t += 2) {
        // prefetch t+1 while computing t
        conv_load(rp0, rp1, rp2, voffA, voffB, Fb1, Fb2);
        rp0 += adv0; rp1 += adv1; rp2 += adv2;
        conv_body(Fa1, Fa2, wpack + t * 72, wrap, acc);
        // prefetch t+2 while computing t+1
        if (t + 2 < TT) {
            conv_load(rp0, rp1, rp2, voffA, voffB, Fa1, Fa2);
            rp0 += adv0; rp1 += adv1; rp2 += adv2;
        }
        conv_body(Fb1, Fb2, wpack + (t + 1) * 72, wrap, acc);
    }

    // relu + per-thread reduce
    float vals[8];
#pragma unroll
    for (int c = 0; c < 8; ++c) vals[c] = 0.f;
    if (active) {
#pragma unroll
        for (int c = 0; c < 4; ++c) {
            float s0 = 0.f;
#pragma unroll
            for (int v = 0; v < 4; ++v) s0 += fmaxf(acc[c][v], 0.f);
            vals[c] = s0;
            float m0 = 0.f;
#pragma unroll
            for (int v = 0; v < 4; ++v) m0 = fmaxf(m0, fmaxf(acc[c + 4][v], 0.f));
            vals[c + 4] = m0;
        }
    }

    // wave butterfly reduce
#pragma unroll
    for (int off = 32; off > 0; off >>= 1) {
#pragma unroll
        for (int c = 0; c < 4; ++c) vals[c] += __shfl_xor(vals[c], off, 64);
#pragma unroll
        for (int c = 4; c < 8; ++c) vals[c] = fmaxf(vals[c], __shfl_xor(vals[c], off, 64));
    }
    __shared__ float wred[4][8];
    const int wv = tid >> 6;
    if (lane == 0) {
#pragma unroll
        for (int c = 0; c < 8; ++c) wred[wv][c] = vals[c];
    }
    __syncthreads();
    if (tid < 8) {
        const float a0 = wred[0][tid], a1 = wred[1][tid], a2 = wred[2][tid], a3 = wred[3][tid];
        const float r = (tid < 4) ? (a0 + a1 + a2 + a3) : fmaxf(fmaxf(a0, a1), fmaxf(a2, a3));
        partials[((size_t)b * 250 + blockIdx.x) * 8 + tid] = r;
    }
}

// ---------------- K7: reduce partials -> topo[b][8] ----------------
__global__ __launch_bounds__(256) void k_topo(const float* __restrict__ partials,
                                              float* __restrict__ topo) {
    const int b = blockIdx.x;
    const int tid = threadIdx.x;
    const int c = tid & 7;
    const int g = tid >> 3;  // 32 groups
    float vs = 0.f, vm = 0.f;
    for (int rp = g; rp < 250; rp += 32) {
        const float v = partials[((size_t)b * 250 + rp) * 8 + c];
        vs += v;
        vm = fmaxf(vm, v);
    }
    __shared__ float red[256];
    red[tid] = (c < 4) ? vs : vm;
    __syncthreads();
    for (int s = 16; s > 0; s >>= 1) {
        if (g < s) {
            const float a = red[tid];
            const float bv = red[tid + s * 8];
            red[tid] = (c < 4) ? (a + bv) : fmaxf(a, bv);
        }
        __syncthreads();
    }
    if (tid < 8) topo[b * 8 + tid] = (tid < 4) ? red[tid] * (1.f / (NN * (float)NN)) : red[tid];
}

// ---------------- K8: assemble output ----------------
__global__ __launch_bounds__(64) void k_out(const float* __restrict__ x,
                                            const float* __restrict__ y1,
                                            const float* __restrict__ y2,
                                            const float* __restrict__ W,
                                            const float* __restrict__ biasN,
                                            const float* __restrict__ wws,
                                            const float* __restrict__ wwt,
                                            const float* __restrict__ M,
                                            const float* __restrict__ wsum,
                                            const float* __restrict__ topo,
                                            float* __restrict__ out) {
    const int bn = blockIdx.x;
    const int b = bn / NN;
    const int n = bn - b * NN;
    const int o = threadIdx.x;
    float val;
    if (o < 48) {
        val = x[bn] * W[n * 144 + o] + y1[bn] * W[n * 144 + 48 + o] + y2[bn] * W[n * 144 + 96 + o];
    } else if (o < 56) {
        const int oo = o - 48;
        val = M[bn] * wws[n * 8 + oo] * topo[b * 8 + oo];
    } else {
        const int oo = o - 56;
        val = wsum[bn] * wwt[n * 8 + oo];
    }
    out[(size_t)bn * 64 + o] = val + biasN[n * 64 + o];
}

extern "C" void kernel_launch(void* const* d_in, const int* in_sizes, int n_in,
                              void* d_out, int out_size, void* d_ws, size_t ws_size,
                              hipStream_t stream) {
    const float* x    = (const float*)d_in[0];
    const float* xw   = (const float*)d_in[1];
    const float* E    = (const float*)d_in[2];
    const float* MPG  = (const float*)d_in[4];
    const int*   bidx = (const int*)d_in[5];
    const int*   stay = (const int*)d_in[7];
    const int*   jump = (const int*)d_in[8];
    const float* wp   = (const float*)d_in[9];
    const float* wwsp = (const float*)d_in[10];
    const float* wwtp = (const float*)d_in[11];
    const float* bp   = (const float*)d_in[12];
    const float* Tp   = (const float*)d_in[13];
    const float* cmw  = (const float*)d_in[14];
    const float* cmb  = (const float*)d_in[15];
    const float* cxw  = (const float*)d_in[16];
    const float* cxb  = (const float*)d_in[17];
    float* out = (float*)d_out;

    float* w = (float*)d_ws;
    float* S     = w;               // 250000
    float* y1    = S + 250000;      // 16000
    float* y2    = y1 + 16000;      // 16000
    float* W     = y2 + 16000;      // 72000
    float* biasN = W + 72000;       // 32000
    float* wws   = biasN + 32000;   // 4000
    float* wwt   = wws + 4000;      // 4000
    float* M     = wwt + 4000;      // 16000
    float* wsum  = M + 16000;       // 16000
    float* parts = wsum + 16000;    // 64000
    float* topo  = parts + 64000;   // 256
    float* zrow  = topo + 256;      // 640 floats zero page
    float* wpck  = zrow + 640;      // 864 floats packed conv weights

    hipMemsetAsync(zrow, 0, 640 * sizeof(float), stream);
    k_wpack<<<4, 256, 0, stream>>>(cmw, cxw, wpck);
    k_softmaxS<<<NN, 256, 0, stream>>>(E, stay, S);
    k_matvecS<<<dim3(125, BB), 256, 0, stream>>>(S, x, y1);
    k_matvecS<<<dim3(125, BB), 256, 0, stream>>>(S, y1, y2);
    k_smallpre<<<NN, 256, 0, stream>>>(E, wp, bp, wwsp, wwtp, W, biasN, wws, wwt);
    k_Mwsum<<<dim3(4, BB), 128, 0, stream>>>(xw, S, bidx, jump, Tp, M, wsum);
    k_conv<<<dim3(250, BB), 256, 0, stream>>>(MPG, wpck, cmb, cxb, zrow, parts);
    k_topo<<<BB, 256, 0, stream>>>(parts, topo);
    k_out<<<BB * NN, 64, 0, stream>>>(x, y1, y2, W, biasN, wws, wwt, M, wsum, topo, out);
}